// Round 7
// baseline (68.099 us; speedup 1.0000x reference)
//
#include <hip/hip_runtime.h>
#include <hip/hip_bf16.h>

#define NMOV 32768
#define LW 15
#define DIM 256
#define NVOC 27
#define NR 405       // NVOC * LW distinct (letter, position) rows
#define GSH 408      // row stride of H in float2 units
#define MPB 16       // moves per block in moves_kernel

__device__ __forceinline__ float b2f(unsigned short u) {
    return __uint_as_float(((unsigned int)u) << 16);
}

// pair index p -> (l<<4 | m), l >= m, p = l(l+1)/2 + m
__device__ const unsigned char PAIR_LUT[120] = {
    0x00,
    0x10,0x11,
    0x20,0x21,0x22,
    0x30,0x31,0x32,0x33,
    0x40,0x41,0x42,0x43,0x44,
    0x50,0x51,0x52,0x53,0x54,0x55,
    0x60,0x61,0x62,0x63,0x64,0x65,0x66,
    0x70,0x71,0x72,0x73,0x74,0x75,0x76,0x77,
    0x80,0x81,0x82,0x83,0x84,0x85,0x86,0x87,0x88,
    0x90,0x91,0x92,0x93,0x94,0x95,0x96,0x97,0x98,0x99,
    0xA0,0xA1,0xA2,0xA3,0xA4,0xA5,0xA6,0xA7,0xA8,0xA9,0xAA,
    0xB0,0xB1,0xB2,0xB3,0xB4,0xB5,0xB6,0xB7,0xB8,0xB9,0xBA,0xBB,
    0xC0,0xC1,0xC2,0xC3,0xC4,0xC5,0xC6,0xC7,0xC8,0xC9,0xCA,0xCB,0xCC,
    0xD0,0xD1,0xD2,0xD3,0xD4,0xD5,0xD6,0xD7,0xD8,0xD9,0xDA,0xDB,0xDC,0xDD,
    0xE0,0xE1,0xE2,0xE3,0xE4,0xE5,0xE6,0xE7,0xE8,0xE9,0xEA,0xEB,0xEC,0xED,0xEE
};

// ---------------------------------------------------------------------------
// Kernel 1: QKV as tiled GEMM  [405 x 256] @ [256 x 768]^T-rows + bias.
// (unchanged from R6)
// ---------------------------------------------------------------------------
__global__ __launch_bounds__(256) void qkv_gemm(
    const float* __restrict__ le, const float* __restrict__ pos,
    const float* __restrict__ Wq, const float* __restrict__ bq,
    const float* __restrict__ Wk, const float* __restrict__ bk,
    const float* __restrict__ Wv, const float* __restrict__ bv,
    float* __restrict__ QT, float* __restrict__ KT,
    __hip_bfloat16* __restrict__ VT)
{
    __shared__ float Ash[32][260];       // emb rows, b128-aligned stride
    __shared__ float Bsh[256][69];       // W transposed: Bsh[k][i] = W[nb+i][k]
    const int t  = threadIdx.x;
    const int gx = blockIdx.x % 12;
    const int gy = blockIdx.x / 12;
    const int r0 = gy * 32;
    const int mat = gx >> 2;             // 0=Q 1=K 2=V
    const int nb  = (gx & 3) * 64;       // col base within mat
    const float* W  = (mat == 0) ? Wq : (mat == 1) ? Wk : Wv;
    const float* bb = (mat == 0) ? bq : (mat == 1) ? bk : bv;

    #pragma unroll
    for (int s = 0; s < 8; ++s) {
        int slot = s * 256 + t;
        int row = slot >> 6, q4 = slot & 63;
        int r = r0 + row;
        float4 v = make_float4(0.f, 0.f, 0.f, 0.f);
        if (r < NR) {
            int c = r / 15, l = r - c * 15;
            float4 lv = *(const float4*)&le[c * DIM + q4 * 4];
            float4 pv = *(const float4*)&pos[l * DIM + q4 * 4];
            v = make_float4(lv.x + pv.x, lv.y + pv.y, lv.z + pv.z, lv.w + pv.w);
        }
        *(float4*)&Ash[row][q4 * 4] = v;
    }
    #pragma unroll
    for (int s = 0; s < 16; ++s) {
        int slot = s * 256 + t;
        int row = slot >> 6, q4 = slot & 63;
        float4 w4 = *(const float4*)&W[(nb + row) * DIM + q4 * 4];
        Bsh[q4 * 4 + 0][row] = w4.x;
        Bsh[q4 * 4 + 1][row] = w4.y;
        Bsh[q4 * 4 + 2][row] = w4.z;
        Bsh[q4 * 4 + 3][row] = w4.w;
    }
    __syncthreads();

    const int tn = t & 63, tm = t >> 6;
    float acc[8];
    #pragma unroll
    for (int rr = 0; rr < 8; ++rr) acc[rr] = 0.f;

    #pragma unroll 4
    for (int kq = 0; kq < 64; ++kq) {
        float4 a4[8];
        #pragma unroll
        for (int rr = 0; rr < 8; ++rr)
            a4[rr] = *(const float4*)&Ash[tm * 8 + rr][kq * 4];
        float b0 = Bsh[kq * 4 + 0][tn];
        float b1 = Bsh[kq * 4 + 1][tn];
        float b2 = Bsh[kq * 4 + 2][tn];
        float b3 = Bsh[kq * 4 + 3][tn];
        #pragma unroll
        for (int rr = 0; rr < 8; ++rr)
            acc[rr] += a4[rr].x * b0 + a4[rr].y * b1 + a4[rr].z * b2 + a4[rr].w * b3;
    }

    const float bias = bb[nb + tn];
    const int dcol = nb + tn;
    #pragma unroll
    for (int rr = 0; rr < 8; ++rr) {
        int r = r0 + tm * 8 + rr;
        if (r < NR) {
            float v = acc[rr] + bias;
            if (mat == 0)      QT[r * DIM + dcol] = v;
            else if (mat == 1) KT[r * DIM + dcol] = v;
            else               VT[r * DIM + dcol] = __float2bfloat16(v);
        }
    }
}

// ---------------------------------------------------------------------------
// Kernel 2: H[i][j] = { G[i][j], G[j][i] } (unchanged from R6)
// ---------------------------------------------------------------------------
__global__ __launch_bounds__(256) void h_matrix(
    const float* __restrict__ QT, const float* __restrict__ KT,
    float2* __restrict__ H)
{
    __shared__ float Qi[16][68], Ki[16][68], Qj[16][68], Kj[16][68];

    int rem = blockIdx.x, bi = 0, cnt = 26;
    while (rem >= cnt) { rem -= cnt; ++bi; --cnt; }
    const int bj = bi + rem;
    const int i0 = bi * 16, j0 = bj * 16;
    const int t = threadIdx.x;
    const int ti = t >> 4, tj = t & 15;

    float acc_ij = 0.f, acc_ji = 0.f;

    for (int k0 = 0; k0 < DIM; k0 += 64) {
        #pragma unroll
        for (int s = 0; s < 4; ++s) {
            int slot = s * 256 + t;
            int tile = slot >> 8;
            int r    = (slot >> 4) & 15;
            int c4   = slot & 15;
            int grow = (tile < 2) ? (i0 + r) : (j0 + r);
            const float* src = (tile == 0 || tile == 2) ? QT : KT;
            float4 v = (grow < NR)
                ? *(const float4*)&src[grow * DIM + k0 + c4 * 4]
                : make_float4(0.f, 0.f, 0.f, 0.f);
            float* dst = (tile == 0) ? &Qi[r][c4 * 4]
                       : (tile == 1) ? &Ki[r][c4 * 4]
                       : (tile == 2) ? &Qj[r][c4 * 4] : &Kj[r][c4 * 4];
            *(float4*)dst = v;
        }
        __syncthreads();
        #pragma unroll 4
        for (int k = 0; k < 64; k += 4) {
            float4 qi = *(const float4*)&Qi[ti][k];
            float4 kj = *(const float4*)&Kj[tj][k];
            float4 qj = *(const float4*)&Qj[ti][k];
            float4 ki = *(const float4*)&Ki[tj][k];
            acc_ij += qi.x * kj.x + qi.y * kj.y + qi.z * kj.z + qi.w * kj.w;
            acc_ji += qj.x * ki.x + qj.y * ki.y + qj.z * ki.z + qj.w * ki.w;
        }
        __syncthreads();
    }

    Qi[ti][tj] = acc_ij;
    Ki[ti][tj] = acc_ji;
    __syncthreads();
    const float t_ij = Qi[tj][ti];
    const float t_ji = Ki[tj][ti];

    const int i1 = i0 + ti, j1 = j0 + tj;
    if (i1 < NR && j1 < NR) H[i1 * GSH + j1] = make_float2(acc_ij, t_ji);
    const int i2 = j0 + ti, j2 = i0 + tj;
    if (i2 < NR && j2 < NR) H[i2 * GSH + j2] = make_float2(acc_ji, t_ij);
}

// ---------------------------------------------------------------------------
// Kernel 3: wave-synchronous per-move pipeline, ZERO __syncthreads.
// MPB=16, 2048 blocks: LDS 18.4KB -> 8 blocks/CU = 32 waves/CU resident.
// Wave w owns moves 4w..4w+3 (all producer/consumer pairs wave-local):
//   phase 1: half-wave gathers for TWO moves -> 8 H-loads in flight/wave
//   softmax + colsum: 60 lanes = 4 moves x 15 rows, all in wave w
//   phase 2: 4 moves/wave, loads in <=12-load batches, unroll 1 (VGPR<=64;
//            the 64-VGPR cliff halves waves/SIMD — R4 lesson).
// NOTE: __launch_bounds__(256) ONLY — a min-waves arg spills to scratch (R4).
// ---------------------------------------------------------------------------
__global__ __launch_bounds__(256) void moves_kernel(
    const int* __restrict__ words, const int* __restrict__ rowsI,
    const int* __restrict__ colsI, const int* __restrict__ dirsI,
    const int* __restrict__ scoresI,
    const float2* __restrict__ H, const __hip_bfloat16* __restrict__ VT,
    const float* __restrict__ row_emb, const float* __restrict__ col_emb,
    const float* __restrict__ dir_emb, const float* __restrict__ score_emb,
    float* __restrict__ out)
{
    __shared__ float S[MPB][LW][17];     // 15x15 score matrix per move (padded)
    __shared__ int   rIdx[MPB][16];      // row indices per move
    __shared__ float csum[MPB][16];      // per-move column sums
    const int base = blockIdx.x * MPB;
    const int t  = threadIdx.x;
    const int w  = t >> 6;               // wave id: owns moves 4w..4w+3
    const int ln = t & 63;
    const int hw = t >> 5;               // half-wave: owns moves 2hw, 2hw+1
    const int j  = t & 31;

    // rIdx: 60 lanes of wave w load 4 moves x 15 positions (coalesced 240B)
    if (ln < 60) {
        int mvl = ln / 15, row = ln - mvl * 15;
        int mv = w * 4 + mvl;
        rIdx[mv][row] = words[(base + mv) * LW + row] * LW + row;
    }
    __builtin_amdgcn_wave_barrier();

    // -------- phase 1: 8 H-gathers in flight per wave (2 moves x 4 pairs)
    const int mv0 = hw * 2, mv1 = mv0 + 1;
    float2 h0[4], h1[4];
    int ll[4], mm[4];
    #pragma unroll
    for (int k = 0; k < 4; ++k) {
        int p = j + 32 * k;
        if (p < 120) {
            int lm = PAIR_LUT[p];
            ll[k] = lm >> 4; mm[k] = lm & 15;
            h0[k] = H[(size_t)rIdx[mv0][ll[k]] * GSH + rIdx[mv0][mm[k]]];
            h1[k] = H[(size_t)rIdx[mv1][ll[k]] * GSH + rIdx[mv1][mm[k]]];
        }
    }
    #pragma unroll
    for (int k = 0; k < 4; ++k) {
        int p = j + 32 * k;
        if (p < 120) {
            S[mv0][ll[k]][mm[k]] = h0[k].x;
            S[mv0][mm[k]][ll[k]] = h0[k].y;
            S[mv1][ll[k]][mm[k]] = h1[k].x;
            S[mv1][mm[k]][ll[k]] = h1[k].y;
        }
    }
    __builtin_amdgcn_wave_barrier();

    // -------- row softmax: lane ln<60 -> (move w*4 + ln/15, row ln%15)
    if (ln < 60) {
        int mvl = ln / 15, row = ln - mvl * 15;
        int mv = w * 4 + mvl;
        float s[LW];
        #pragma unroll
        for (int m = 0; m < LW; ++m) s[m] = S[mv][row][m];
        float mx = s[0];
        #pragma unroll
        for (int m = 1; m < LW; ++m) mx = fmaxf(mx, s[m]);
        float sum = 0.f;
        #pragma unroll
        for (int m = 0; m < LW; ++m) { s[m] = __expf(s[m] - mx); sum += s[m]; }
        float inv = 1.0f / sum;
        #pragma unroll
        for (int m = 0; m < LW; ++m) S[mv][row][m] = s[m] * inv;
    }
    __builtin_amdgcn_wave_barrier();

    // -------- column sums: lane ln<60 -> (move, column)
    if (ln < 60) {
        int mvl = ln / 15, col = ln - mvl * 15;
        int mv = w * 4 + mvl;
        float acc = 0.f;
        #pragma unroll
        for (int l = 0; l < LW; ++l) acc += S[mv][l][col];
        csum[mv][col] = acc;
    }
    __builtin_amdgcn_wave_barrier();

    // -------- phase 2: wave w handles moves 4w..4w+3
    const int d0 = ln * 4;
    const unsigned short* VT16 = (const unsigned short*)VT;
    #pragma unroll 1
    for (int s2 = 0; s2 < 4; ++s2) {
        const int i = w * 4 + s2;
        const int n = base + i;
        // batch 1: epilogue rows + first 8 VT rows
        float4 re = *(const float4*)&row_emb[rowsI[n] * DIM + d0];
        float4 ce = *(const float4*)&col_emb[colsI[n] * DIM + d0];
        float4 de = *(const float4*)&dir_emb[dirsI[n] * DIM + d0];
        float4 se = *(const float4*)&score_emb[min(scoresI[n], 99) * DIM + d0];
        ushort4 va[8];
        #pragma unroll
        for (int m = 0; m < 8; ++m)
            va[m] = *(const ushort4*)(VT16 + (size_t)rIdx[i][m] * DIM + d0);
        float wx = 0.f, wy = 0.f, wz = 0.f, ww = 0.f;
        #pragma unroll
        for (int m = 0; m < 8; ++m) {
            float c = csum[i][m];
            wx += c * b2f(va[m].x); wy += c * b2f(va[m].y);
            wz += c * b2f(va[m].z); ww += c * b2f(va[m].w);
        }
        // batch 2: remaining 7 VT rows
        ushort4 vb[7];
        #pragma unroll
        for (int m = 0; m < 7; ++m)
            vb[m] = *(const ushort4*)(VT16 + (size_t)rIdx[i][8 + m] * DIM + d0);
        #pragma unroll
        for (int m = 0; m < 7; ++m) {
            float c = csum[i][8 + m];
            wx += c * b2f(vb[m].x); wy += c * b2f(vb[m].y);
            wz += c * b2f(vb[m].z); ww += c * b2f(vb[m].w);
        }
        float4 res;
        res.x = 2.f * wx + re.x + ce.x + de.x + se.x;
        res.y = 2.f * wy + re.y + ce.y + de.y + se.y;
        res.z = 2.f * wz + re.z + ce.z + de.z + se.z;
        res.w = 2.f * ww + re.w + ce.w + de.w + se.w;
        *(float4*)&out[(size_t)n * DIM + d0] = res;
    }
}

extern "C" void kernel_launch(void* const* d_in, const int* in_sizes, int n_in,
                              void* d_out, int out_size, void* d_ws, size_t ws_size,
                              hipStream_t stream)
{
    const int*   words      = (const int*)d_in[0];
    const int*   rowsI      = (const int*)d_in[1];
    const int*   colsI      = (const int*)d_in[2];
    const int*   dirsI      = (const int*)d_in[3];
    const int*   scoresI    = (const int*)d_in[4];
    const float* letter_emb = (const float*)d_in[5];
    const float* positional = (const float*)d_in[6];
    const float* Wq         = (const float*)d_in[7];
    const float* bq         = (const float*)d_in[8];
    const float* Wk         = (const float*)d_in[9];
    const float* bk         = (const float*)d_in[10];
    const float* Wv         = (const float*)d_in[11];
    const float* bv         = (const float*)d_in[12];
    const float* row_emb    = (const float*)d_in[13];
    const float* col_emb    = (const float*)d_in[14];
    const float* dir_emb    = (const float*)d_in[15];
    const float* score_emb  = (const float*)d_in[16];
    float* out = (float*)d_out;

    // workspace (bytes): QT f32[405*256] | KT f32[405*256] | H f2[405*408] | VT bf16[405*256]
    float*  QT = (float*)d_ws;
    float*  KT = QT + NR * DIM;
    float2* Hm = (float2*)(KT + NR * DIM);
    __hip_bfloat16* VT = (__hip_bfloat16*)((char*)Hm + (size_t)NR * GSH * sizeof(float2));

    qkv_gemm<<<156, 256, 0, stream>>>(letter_emb, positional, Wq, bq, Wk, bk,
                                      Wv, bv, QT, KT, VT);
    h_matrix<<<351, 256, 0, stream>>>(QT, KT, Hm);
    moves_kernel<<<NMOV / MPB, 256, 0, stream>>>(words, rowsI, colsI, dirsI,
                                                 scoresI, Hm, VT, row_emb,
                                                 col_emb, dir_emb, score_emb,
                                                 out);
}

// Round 8
// 63.197 us; speedup vs baseline: 1.0776x; 1.0776x over previous
//
#include <hip/hip_runtime.h>
#include <hip/hip_bf16.h>

#define NMOV 32768
#define LW 15
#define DIM 256
#define NVOC 27
#define NR 405       // NVOC * LW distinct (letter, position) rows
#define GSH 408      // row stride of H in float2 units
#define MPB 16       // moves per block in moves_kernel

__device__ __forceinline__ float b2f(unsigned short u) {
    return __uint_as_float(((unsigned int)u) << 16);
}

// pair index p -> (l<<4 | m), l >= m, p = l(l+1)/2 + m
__device__ const unsigned char PAIR_LUT[120] = {
    0x00,
    0x10,0x11,
    0x20,0x21,0x22,
    0x30,0x31,0x32,0x33,
    0x40,0x41,0x42,0x43,0x44,
    0x50,0x51,0x52,0x53,0x54,0x55,
    0x60,0x61,0x62,0x63,0x64,0x65,0x66,
    0x70,0x71,0x72,0x73,0x74,0x75,0x76,0x77,
    0x80,0x81,0x82,0x83,0x84,0x85,0x86,0x87,0x88,
    0x90,0x91,0x92,0x93,0x94,0x95,0x96,0x97,0x98,0x99,
    0xA0,0xA1,0xA2,0xA3,0xA4,0xA5,0xA6,0xA7,0xA8,0xA9,0xAA,
    0xB0,0xB1,0xB2,0xB3,0xB4,0xB5,0xB6,0xB7,0xB8,0xB9,0xBA,0xBB,
    0xC0,0xC1,0xC2,0xC3,0xC4,0xC5,0xC6,0xC7,0xC8,0xC9,0xCA,0xCB,0xCC,
    0xD0,0xD1,0xD2,0xD3,0xD4,0xD5,0xD6,0xD7,0xD8,0xD9,0xDA,0xDB,0xDC,0xDD,
    0xE0,0xE1,0xE2,0xE3,0xE4,0xE5,0xE6,0xE7,0xE8,0xE9,0xEA,0xEB,0xEC,0xED,0xEE
};

// ---------------------------------------------------------------------------
// Kernel 1 v3: QKV GEMM, h_matrix-style 16x16 tiles, full K in LDS.
// Grid 26 x 48 = 1248 blocks (vs 156 at 1 block/CU before): by = 16-row tile
// of emb, bx = 16-col tile of (Wq|Wk|Wv). A built from le+pos on the fly.
// LDS 33KB -> 4 blocks/CU. One output per thread via LDS row-dot.
// ---------------------------------------------------------------------------
__global__ __launch_bounds__(256) void qkv_gemm(
    const float* __restrict__ le, const float* __restrict__ pos,
    const float* __restrict__ Wq, const float* __restrict__ bq,
    const float* __restrict__ Wk, const float* __restrict__ bk,
    const float* __restrict__ Wv, const float* __restrict__ bv,
    float* __restrict__ QT, float* __restrict__ KT,
    __hip_bfloat16* __restrict__ VT)
{
    __shared__ float Ash[16][260];
    __shared__ float Bsh[16][260];
    const int t  = threadIdx.x;
    const int bx = blockIdx.x % 48;
    const int by = blockIdx.x / 48;
    const int r0 = by * 16;
    const int mat = bx >> 4;             // 0=Q 1=K 2=V
    const int nb  = (bx & 15) * 16;      // col base within mat
    const float* W  = (mat == 0) ? Wq : (mat == 1) ? Wk : Wv;
    const float* bb = (mat == 0) ? bq : (mat == 1) ? bk : bv;

    // stage A (emb rows r0..r0+15) and B (W rows nb..nb+15), coalesced
    #pragma unroll
    for (int s = 0; s < 4; ++s) {
        int slot = s * 256 + t;          // 1024 float4 slots per tile
        int row = slot >> 6, q4 = slot & 63;
        int r = r0 + row;
        float4 va = make_float4(0.f, 0.f, 0.f, 0.f);
        if (r < NR) {
            int c = r / 15, l = r - c * 15;
            float4 lv = *(const float4*)&le[c * DIM + q4 * 4];
            float4 pv = *(const float4*)&pos[l * DIM + q4 * 4];
            va = make_float4(lv.x + pv.x, lv.y + pv.y, lv.z + pv.z, lv.w + pv.w);
        }
        *(float4*)&Ash[row][q4 * 4] = va;
        float4 vb = *(const float4*)&W[(nb + row) * DIM + q4 * 4];
        *(float4*)&Bsh[row][q4 * 4] = vb;
    }
    __syncthreads();

    const int tj = t & 15, ti = t >> 4;  // output (row ti, col tj) of tile
    float acc = 0.f;
    #pragma unroll 8
    for (int k = 0; k < DIM; k += 4) {
        float4 a = *(const float4*)&Ash[ti][k];
        float4 b = *(const float4*)&Bsh[tj][k];
        acc += a.x * b.x + a.y * b.y + a.z * b.z + a.w * b.w;
    }

    const int r = r0 + ti;
    if (r < NR) {
        float v = acc + bb[nb + tj];
        int dcol = nb + tj;
        if (mat == 0)      QT[r * DIM + dcol] = v;
        else if (mat == 1) KT[r * DIM + dcol] = v;
        else               VT[r * DIM + dcol] = __float2bfloat16(v);
    }
}

// ---------------------------------------------------------------------------
// Kernel 2: H[i][j] = { G[i][j], G[j][i] } (unchanged)
// ---------------------------------------------------------------------------
__global__ __launch_bounds__(256) void h_matrix(
    const float* __restrict__ QT, const float* __restrict__ KT,
    float2* __restrict__ H)
{
    __shared__ float Qi[16][68], Ki[16][68], Qj[16][68], Kj[16][68];

    int rem = blockIdx.x, bi = 0, cnt = 26;
    while (rem >= cnt) { rem -= cnt; ++bi; --cnt; }
    const int bj = bi + rem;
    const int i0 = bi * 16, j0 = bj * 16;
    const int t = threadIdx.x;
    const int ti = t >> 4, tj = t & 15;

    float acc_ij = 0.f, acc_ji = 0.f;

    for (int k0 = 0; k0 < DIM; k0 += 64) {
        #pragma unroll
        for (int s = 0; s < 4; ++s) {
            int slot = s * 256 + t;
            int tile = slot >> 8;
            int r    = (slot >> 4) & 15;
            int c4   = slot & 15;
            int grow = (tile < 2) ? (i0 + r) : (j0 + r);
            const float* src = (tile == 0 || tile == 2) ? QT : KT;
            float4 v = (grow < NR)
                ? *(const float4*)&src[grow * DIM + k0 + c4 * 4]
                : make_float4(0.f, 0.f, 0.f, 0.f);
            float* dst = (tile == 0) ? &Qi[r][c4 * 4]
                       : (tile == 1) ? &Ki[r][c4 * 4]
                       : (tile == 2) ? &Qj[r][c4 * 4] : &Kj[r][c4 * 4];
            *(float4*)dst = v;
        }
        __syncthreads();
        #pragma unroll 4
        for (int k = 0; k < 64; k += 4) {
            float4 qi = *(const float4*)&Qi[ti][k];
            float4 kj = *(const float4*)&Kj[tj][k];
            float4 qj = *(const float4*)&Qj[ti][k];
            float4 ki = *(const float4*)&Ki[tj][k];
            acc_ij += qi.x * kj.x + qi.y * kj.y + qi.z * kj.z + qi.w * kj.w;
            acc_ji += qj.x * ki.x + qj.y * ki.y + qj.z * ki.z + qj.w * ki.w;
        }
        __syncthreads();
    }

    Qi[ti][tj] = acc_ij;
    Ki[ti][tj] = acc_ji;
    __syncthreads();
    const float t_ij = Qi[tj][ti];
    const float t_ji = Ki[tj][ti];

    const int i1 = i0 + ti, j1 = j0 + tj;
    if (i1 < NR && j1 < NR) H[i1 * GSH + j1] = make_float2(acc_ij, t_ji);
    const int i2 = j0 + ti, j2 = i0 + tj;
    if (i2 < NR && j2 < NR) H[i2 * GSH + j2] = make_float2(acc_ji, t_ij);
}

// ---------------------------------------------------------------------------
// Kernel 3: wave-synchronous per-move pipeline, ZERO __syncthreads.
// Change vs R7: META HOIST — all 4 index loads per move issued at kernel
// start by the owning wave (lanes 0..15 -> LDS), so phase 2's
// index-load -> emb-row-load dependent chain collapses to one level
// resolved ~2000 cycles early.
// NOTE: __launch_bounds__(256) ONLY — a min-waves arg spills to scratch (R4).
// ---------------------------------------------------------------------------
__global__ __launch_bounds__(256) void moves_kernel(
    const int* __restrict__ words, const int* __restrict__ rowsI,
    const int* __restrict__ colsI, const int* __restrict__ dirsI,
    const int* __restrict__ scoresI,
    const float2* __restrict__ H, const __hip_bfloat16* __restrict__ VT,
    const float* __restrict__ row_emb, const float* __restrict__ col_emb,
    const float* __restrict__ dir_emb, const float* __restrict__ score_emb,
    float* __restrict__ out)
{
    __shared__ float S[MPB][LW][17];     // 15x15 score matrix per move (padded)
    __shared__ int   rIdx[MPB][16];      // row indices per move
    __shared__ float csum[MPB][16];      // per-move column sums
    __shared__ int   meta[MPB][4];       // rows, cols, dirs, score (clamped)
    const int base = blockIdx.x * MPB;
    const int t  = threadIdx.x;
    const int w  = t >> 6;               // wave id: owns moves 4w..4w+3
    const int ln = t & 63;
    const int hw = t >> 5;               // half-wave: owns moves 2hw, 2hw+1
    const int j  = t & 31;

    // rIdx + meta: loaded by the OWNING wave's lanes (wave-local LDS)
    if (ln < 60) {
        int mvl = ln / 15, row = ln - mvl * 15;
        int mv = w * 4 + mvl;
        rIdx[mv][row] = words[(base + mv) * LW + row] * LW + row;
    }
    if (ln < 16) {
        int mvl = ln >> 2, f = ln & 3;
        int n = base + w * 4 + mvl;
        int v = (f == 0) ? rowsI[n] : (f == 1) ? colsI[n]
              : (f == 2) ? dirsI[n] : min(scoresI[n], 99);
        meta[w * 4 + mvl][f] = v;
    }
    __builtin_amdgcn_wave_barrier();

    // -------- phase 1: 8 H-gathers in flight per wave (2 moves x 4 pairs)
    const int mv0 = hw * 2, mv1 = mv0 + 1;
    float2 h0[4], h1[4];
    int ll[4], mm[4];
    #pragma unroll
    for (int k = 0; k < 4; ++k) {
        int p = j + 32 * k;
        if (p < 120) {
            int lm = PAIR_LUT[p];
            ll[k] = lm >> 4; mm[k] = lm & 15;
            h0[k] = H[(size_t)rIdx[mv0][ll[k]] * GSH + rIdx[mv0][mm[k]]];
            h1[k] = H[(size_t)rIdx[mv1][ll[k]] * GSH + rIdx[mv1][mm[k]]];
        }
    }
    #pragma unroll
    for (int k = 0; k < 4; ++k) {
        int p = j + 32 * k;
        if (p < 120) {
            S[mv0][ll[k]][mm[k]] = h0[k].x;
            S[mv0][mm[k]][ll[k]] = h0[k].y;
            S[mv1][ll[k]][mm[k]] = h1[k].x;
            S[mv1][mm[k]][ll[k]] = h1[k].y;
        }
    }
    __builtin_amdgcn_wave_barrier();

    // -------- row softmax: lane ln<60 -> (move w*4 + ln/15, row ln%15)
    if (ln < 60) {
        int mvl = ln / 15, row = ln - mvl * 15;
        int mv = w * 4 + mvl;
        float s[LW];
        #pragma unroll
        for (int m = 0; m < LW; ++m) s[m] = S[mv][row][m];
        float mx = s[0];
        #pragma unroll
        for (int m = 1; m < LW; ++m) mx = fmaxf(mx, s[m]);
        float sum = 0.f;
        #pragma unroll
        for (int m = 0; m < LW; ++m) { s[m] = __expf(s[m] - mx); sum += s[m]; }
        float inv = 1.0f / sum;
        #pragma unroll
        for (int m = 0; m < LW; ++m) S[mv][row][m] = s[m] * inv;
    }
    __builtin_amdgcn_wave_barrier();

    // -------- column sums: lane ln<60 -> (move, column)
    if (ln < 60) {
        int mvl = ln / 15, col = ln - mvl * 15;
        int mv = w * 4 + mvl;
        float acc = 0.f;
        #pragma unroll
        for (int l = 0; l < LW; ++l) acc += S[mv][l][col];
        csum[mv][col] = acc;
    }
    __builtin_amdgcn_wave_barrier();

    // -------- phase 2: wave w handles moves 4w..4w+3
    const int d0 = ln * 4;
    const unsigned short* VT16 = (const unsigned short*)VT;
    #pragma unroll 1
    for (int s2 = 0; s2 < 4; ++s2) {
        const int i = w * 4 + s2;
        const int n = base + i;
        // batch 1: epilogue rows (indices pre-resolved in LDS) + 8 VT rows
        float4 re = *(const float4*)&row_emb[meta[i][0] * DIM + d0];
        float4 ce = *(const float4*)&col_emb[meta[i][1] * DIM + d0];
        float4 de = *(const float4*)&dir_emb[meta[i][2] * DIM + d0];
        float4 se = *(const float4*)&score_emb[meta[i][3] * DIM + d0];
        ushort4 va[8];
        #pragma unroll
        for (int m = 0; m < 8; ++m)
            va[m] = *(const ushort4*)(VT16 + (size_t)rIdx[i][m] * DIM + d0);
        float wx = 0.f, wy = 0.f, wz = 0.f, ww = 0.f;
        #pragma unroll
        for (int m = 0; m < 8; ++m) {
            float c = csum[i][m];
            wx += c * b2f(va[m].x); wy += c * b2f(va[m].y);
            wz += c * b2f(va[m].z); ww += c * b2f(va[m].w);
        }
        // batch 2: remaining 7 VT rows
        ushort4 vb[7];
        #pragma unroll
        for (int m = 0; m < 7; ++m)
            vb[m] = *(const ushort4*)(VT16 + (size_t)rIdx[i][8 + m] * DIM + d0);
        #pragma unroll
        for (int m = 0; m < 7; ++m) {
            float c = csum[i][8 + m];
            wx += c * b2f(vb[m].x); wy += c * b2f(vb[m].y);
            wz += c * b2f(vb[m].z); ww += c * b2f(vb[m].w);
        }
        float4 res;
        res.x = 2.f * wx + re.x + ce.x + de.x + se.x;
        res.y = 2.f * wy + re.y + ce.y + de.y + se.y;
        res.z = 2.f * wz + re.z + ce.z + de.z + se.z;
        res.w = 2.f * ww + re.w + ce.w + de.w + se.w;
        *(float4*)&out[(size_t)n * DIM + d0] = res;
    }
}

extern "C" void kernel_launch(void* const* d_in, const int* in_sizes, int n_in,
                              void* d_out, int out_size, void* d_ws, size_t ws_size,
                              hipStream_t stream)
{
    const int*   words      = (const int*)d_in[0];
    const int*   rowsI      = (const int*)d_in[1];
    const int*   colsI      = (const int*)d_in[2];
    const int*   dirsI      = (const int*)d_in[3];
    const int*   scoresI    = (const int*)d_in[4];
    const float* letter_emb = (const float*)d_in[5];
    const float* positional = (const float*)d_in[6];
    const float* Wq         = (const float*)d_in[7];
    const float* bq         = (const float*)d_in[8];
    const float* Wk         = (const float*)d_in[9];
    const float* bk         = (const float*)d_in[10];
    const float* Wv         = (const float*)d_in[11];
    const float* bv         = (const float*)d_in[12];
    const float* row_emb    = (const float*)d_in[13];
    const float* col_emb    = (const float*)d_in[14];
    const float* dir_emb    = (const float*)d_in[15];
    const float* score_emb  = (const float*)d_in[16];
    float* out = (float*)d_out;

    // workspace (bytes): QT f32[405*256] | KT f32[405*256] | H f2[405*408] | VT bf16[405*256]
    float*  QT = (float*)d_ws;
    float*  KT = QT + NR * DIM;
    float2* Hm = (float2*)(KT + NR * DIM);
    __hip_bfloat16* VT = (__hip_bfloat16*)((char*)Hm + (size_t)NR * GSH * sizeof(float2));

    qkv_gemm<<<26 * 48, 256, 0, stream>>>(letter_emb, positional, Wq, bq, Wk, bk,
                                          Wv, bv, QT, KT, VT);
    h_matrix<<<351, 256, 0, stream>>>(QT, KT, Hm);
    moves_kernel<<<NMOV / MPB, 256, 0, stream>>>(words, rowsI, colsI, dirsI,
                                                 scoresI, Hm, VT, row_emb,
                                                 col_emb, dir_emb, score_emb,
                                                 out);
}